// Round 4
// baseline (34768.988 us; speedup 1.0000x reference)
//
#include <hip/hip_runtime.h>

#define LEAKY(v) ((v) >= 0.f ? (v) : 0.01f * (v))

// ---------------- Layer 1 (CIN=3, PH=1, dual tower) ----------------
// grid (1, 15, 32), block 256. blockIdx.z = z*16 + cout_group(4 couts).
__global__ void conv3(const float* __restrict__ in, int inRow0,
                      const float* __restrict__ w0, const float* __restrict__ b0,
                      const float* __restrict__ w1, const float* __restrict__ b1,
                      float* __restrict__ out, int outZS)
{
    const int wcol = threadIdx.x;
    const int h  = blockIdx.y;        // 0..14
    const int cg = blockIdx.z & 15;
    const int z  = blockIdx.z >> 4;
    const float* W  = (z ? w1 : w0) + cg * 4 * 27;
    const float* Bv = z ? b1 : b0;

    float acc[4];
    #pragma unroll
    for (int j = 0; j < 4; ++j) acc[j] = Bv[cg * 4 + j];

    #pragma unroll
    for (int kh = 0; kh < 3; ++kh) {
        const int r = h - 1 + kh;
        const bool valid = (r >= 0 && r < 15);          // slice zero-pad
        const float msk = valid ? 1.f : 0.f;
        const float* rr = in + (inRow0 + (valid ? r : 0)) * 256;
        #pragma unroll
        for (int c = 0; c < 3; ++c) {
            const float* rc = rr + c * 31 * 256;        // ebuf channel stride
            float vm = (wcol > 0)   ? rc[wcol - 1] : 0.f;
            float v0 = rc[wcol];
            float vp = (wcol < 255) ? rc[wcol + 1] : 0.f;
            vm *= msk; v0 *= msk; vp *= msk;
            #pragma unroll
            for (int j = 0; j < 4; ++j) {
                const float* wj = W + j * 27 + c * 9 + kh * 3;
                acc[j] += vm * wj[0] + v0 * wj[1] + vp * wj[2];
            }
        }
    }
    float* o = out + (size_t)z * outZS;
    #pragma unroll
    for (int j = 0; j < 4; ++j)
        o[(cg * 4 + j) * 15 * 256 + h * 256 + wcol] = LEAKY(acc[j]);
}

// ---------------- CIN=64, PH=0 conv: FULL cin unroll ----------------
// grid (1, HOUT, (64/NCO)*NZ), block 256. Thread: 1 col, NCO couts, 1 row.
// Input rows h..h+2 always valid (Hin = HOUT + 2, contiguous slab).
template<int HOUT, int NCO>
__global__ void convT(const float* __restrict__ in, int inChS, int inZS,
                      const float* __restrict__ w0, const float* __restrict__ b0,
                      const float* __restrict__ w1, const float* __restrict__ b1,
                      float* __restrict__ out, int outZS)
{
    constexpr int NCG = 64 / NCO;
    const int wcol = threadIdx.x;
    const int h  = blockIdx.y;
    const int cg = blockIdx.z % NCG;
    const int z  = blockIdx.z / NCG;
    const float* W  = (z ? w1 : w0) + cg * NCO * 576;   // 64*9 per cout
    const float* Bv = z ? b1 : b0;
    const float* ib = in + (size_t)z * inZS + h * 256;
    float* o = out + (size_t)z * outZS;

    const bool mL = (wcol > 0), mR = (wcol < 255);

    float acc[NCO];
    #pragma unroll
    for (int j = 0; j < NCO; ++j) acc[j] = Bv[cg * NCO + j];

    #pragma unroll
    for (int cin = 0; cin < 64; ++cin) {
        const float* r_ = ib + cin * inChS;
        float v[9];
        #pragma unroll
        for (int kh = 0; kh < 3; ++kh) {
            const float* rr = r_ + kh * 256;
            v[kh * 3 + 0] = mL ? rr[wcol - 1] : 0.f;
            v[kh * 3 + 1] = rr[wcol];
            v[kh * 3 + 2] = mR ? rr[wcol + 1] : 0.f;
        }
        #pragma unroll
        for (int j = 0; j < NCO; ++j) {
            const float* wj = W + j * 576 + cin * 9;
            #pragma unroll
            for (int t = 0; t < 9; ++t) acc[j] += v[t] * wj[t];
        }
    }

    const int ohw = HOUT * 256;
    #pragma unroll
    for (int j = 0; j < NCO; ++j)
        o[(cg * NCO + j) * ohw + h * 256 + wcol] = LEAKY(acc[j]);
}

// ---------------- Per-pixel 8x8 @ 8x8 ----------------
__global__ void mm88(const float* __restrict__ tw, float* __restrict__ p0)
{
    const int idx = blockIdx.x * 256 + threadIdx.x;   // pixel in 9*256
    const float* s = tw;
    const float* e = tw + 64 * 9 * 256;
    float sv[64];
    #pragma unroll
    for (int c = 0; c < 64; ++c) sv[c] = s[c * 9 * 256 + idx];
    #pragma unroll
    for (int i = 0; i < 8; ++i) {
        float ev[8];
        #pragma unroll
        for (int j = 0; j < 8; ++j) ev[j] = e[(i * 8 + j) * 9 * 256 + idx];
        #pragma unroll
        for (int k = 0; k < 8; ++k) {
            float acc = 0.f;
            #pragma unroll
            for (int j = 0; j < 8; ++j) acc += ev[j] * sv[j * 8 + k];
            p0[(i * 8 + k) * 9 * 256 + idx] = acc;
        }
    }
}

// ---------------- conv9 (64->3, kh=1 taps only) + recurrence update ----------------
// block (256,4): threadIdx.y owns 16 cins, fully unrolled; LDS reduce.
__global__ void conv9up(const float* __restrict__ pin, const float* __restrict__ w9,
                        const float* __restrict__ b9, const float* __restrict__ x,
                        float* __restrict__ ebuf, float* __restrict__ preds, int i)
{
    const int wcol = threadIdx.x;
    const int yq   = threadIdx.y;       // 0..3
    const int c0   = yq * 16;
    const bool mL = (wcol > 0), mR = (wcol < 255);
    float a0 = 0.f, a1 = 0.f, a2 = 0.f;

    #pragma unroll
    for (int c = 0; c < 16; ++c) {
        const int cin = c0 + c;
        const float* r_ = pin + cin * 256;
        float vm = mL ? r_[wcol - 1] : 0.f;
        float v0 = r_[wcol];
        float vp = mR ? r_[wcol + 1] : 0.f;
        const float* wk0 = w9 + (0 * 64 + cin) * 9 + 3;   // kh=1
        const float* wk1 = w9 + (1 * 64 + cin) * 9 + 3;
        const float* wk2 = w9 + (2 * 64 + cin) * 9 + 3;
        a0 += vm * wk0[0] + v0 * wk0[1] + vp * wk0[2];
        a1 += vm * wk1[0] + v0 * wk1[1] + vp * wk1[2];
        a2 += vm * wk2[0] + v0 * wk2[1] + vp * wk2[2];
    }

    __shared__ float red[4][3][256];
    red[yq][0][wcol] = a0;
    red[yq][1][wcol] = a1;
    red[yq][2][wcol] = a2;
    __syncthreads();

    if (yq == 0) {
        #pragma unroll
        for (int j = 0; j < 3; ++j) {
            float v = b9[j] + red[0][j][wcol] + red[1][j][wcol]
                            + red[2][j][wcol] + red[3][j][wcol];
            v = LEAKY(v);
            preds[i * 768 + j * 256 + wcol] = v;
            ebuf[j * 31 * 256 + (15 + i) * 256 + wcol] =
                x[j * 31 * 256 + (15 + i) * 256 + wcol] - v;
        }
    }
}

// ---------------- finalize ----------------
__global__ void finalize(const float* __restrict__ preds, const float* __restrict__ ebuf,
                         float* __restrict__ o)
{
    const int idx = blockIdx.x * 256 + threadIdx.x;
    if (idx >= 24576) return;
    if (idx < 12288) {
        const int c = idx >> 12;
        const int t = (idx >> 8) & 15;
        const int w = idx & 255;
        o[idx] = preds[t * 768 + c * 256 + w];
    } else {
        const int j = idx - 12288;
        const int c = j >> 12;
        const int t = (j >> 8) & 15;
        const int w = j & 255;
        o[idx] = ebuf[c * 31 * 256 + (15 + t) * 256 + w];
    }
}

extern "C" void kernel_launch(void* const* d_in, const int* in_sizes, int n_in,
                              void* d_out, int out_size, void* d_ws, size_t ws_size,
                              hipStream_t stream)
{
    const float* x   = (const float*)d_in[0];
    const float* w1x = (const float*)d_in[1];  const float* b1x = (const float*)d_in[2];
    const float* w2x = (const float*)d_in[3];  const float* b2x = (const float*)d_in[4];
    const float* w3x = (const float*)d_in[5];  const float* b3x = (const float*)d_in[6];
    const float* w4x = (const float*)d_in[7];  const float* b4x = (const float*)d_in[8];
    const float* w1e = (const float*)d_in[9];  const float* b1e = (const float*)d_in[10];
    const float* w2e = (const float*)d_in[11]; const float* b2e = (const float*)d_in[12];
    const float* w3e = (const float*)d_in[13]; const float* b3e = (const float*)d_in[14];
    const float* w4e = (const float*)d_in[15]; const float* b4e = (const float*)d_in[16];
    const float* w5  = (const float*)d_in[17]; const float* b5  = (const float*)d_in[18];
    const float* w6  = (const float*)d_in[19]; const float* b6  = (const float*)d_in[20];
    const float* w7  = (const float*)d_in[21]; const float* b7  = (const float*)d_in[22];
    const float* w8  = (const float*)d_in[23]; const float* b8  = (const float*)d_in[24];
    const float* w9  = (const float*)d_in[25]; const float* b9  = (const float*)d_in[26];

    float* ws    = (float*)d_ws;
    float* ebuf  = ws;                   // 3*31*256    = 23808
    float* tA    = ebuf + 23808;         // 2*64*15*256 = 491520
    float* tB    = tA + 491520;          // 2*64*15*256 = 491520
    float* p0    = tB + 491520;          // 64*9*256    = 147456
    float* p1    = p0 + 147456;          // 64*9*256    = 147456
    float* preds = p1 + 147456;          // 16*3*256    = 12288

    hipMemcpyAsync(ebuf, x, 23808 * sizeof(float), hipMemcpyDeviceToDevice, stream);

    for (int i = 0; i < 16; ++i) {
        conv3<<<dim3(1, 15, 32), 256, 0, stream>>>(ebuf, i, w1x, b1x, w1e, b1e,
                                                   tA, 64 * 15 * 256);
        convT<13, 4><<<dim3(1, 13, 32), 256, 0, stream>>>(tA, 15 * 256, 64 * 15 * 256,
                                                          w2x, b2x, w2e, b2e,
                                                          tB, 64 * 13 * 256);
        convT<11, 4><<<dim3(1, 11, 32), 256, 0, stream>>>(tB, 13 * 256, 64 * 13 * 256,
                                                          w3x, b3x, w3e, b3e,
                                                          tA, 64 * 11 * 256);
        convT<9, 4><<<dim3(1, 9, 32), 256, 0, stream>>>(tA, 11 * 256, 64 * 11 * 256,
                                                        w4x, b4x, w4e, b4e,
                                                        tB, 64 * 9 * 256);
        mm88<<<9, 256, 0, stream>>>(tB, p0);
        convT<7, 2><<<dim3(1, 7, 32), 256, 0, stream>>>(p0, 9 * 256, 0,
                                                        w5, b5, w5, b5, p1, 0);
        convT<5, 2><<<dim3(1, 5, 32), 256, 0, stream>>>(p1, 7 * 256, 0,
                                                        w6, b6, w6, b6, p0, 0);
        convT<3, 2><<<dim3(1, 3, 32), 256, 0, stream>>>(p0, 5 * 256, 0,
                                                        w7, b7, w7, b7, p1, 0);
        convT<1, 2><<<dim3(1, 1, 32), 256, 0, stream>>>(p1, 3 * 256, 0,
                                                        w8, b8, w8, b8, p0, 0);
        conv9up<<<dim3(1, 1, 1), dim3(256, 4), 0, stream>>>(p0, w9, b9, x, ebuf, preds, i);
    }

    finalize<<<96, 256, 0, stream>>>(preds, ebuf, (float*)d_out);
}

// Round 5
// 10018.442 us; speedup vs baseline: 3.4705x; 3.4705x over previous
//
#include <hip/hip_runtime.h>

#define LEAKY(v) ((v) >= 0.f ? (v) : 0.01f * (v))

// ---------------- Layer 1 (CIN=3, PH=1, dual tower) ----------------
// grid (1, 15, 32), block 256. blockIdx.z = z*16 + cout_group(4 couts).
__global__ void conv3(const float* __restrict__ in, int inRow0,
                      const float* __restrict__ w0, const float* __restrict__ b0,
                      const float* __restrict__ w1, const float* __restrict__ b1,
                      float* __restrict__ out, int outZS)
{
    const int wcol = threadIdx.x;
    const int h  = blockIdx.y;        // 0..14
    const int cg = blockIdx.z & 15;
    const int z  = blockIdx.z >> 4;
    const float* W  = (z ? w1 : w0) + cg * 4 * 27;
    const float* Bv = z ? b1 : b0;

    float acc[4];
    #pragma unroll
    for (int j = 0; j < 4; ++j) acc[j] = Bv[cg * 4 + j];

    #pragma unroll
    for (int kh = 0; kh < 3; ++kh) {
        const int r = h - 1 + kh;
        const bool valid = (r >= 0 && r < 15);          // slice zero-pad
        const float msk = valid ? 1.f : 0.f;
        const float* rr = in + (inRow0 + (valid ? r : 0)) * 256;
        #pragma unroll
        for (int c = 0; c < 3; ++c) {
            const float* rc = rr + c * 31 * 256;        // ebuf channel stride
            float vm = (wcol > 0)   ? rc[wcol - 1] : 0.f;
            float v0 = rc[wcol];
            float vp = (wcol < 255) ? rc[wcol + 1] : 0.f;
            vm *= msk; v0 *= msk; vp *= msk;
            #pragma unroll
            for (int j = 0; j < 4; ++j) {
                const float* wj = W + j * 27 + c * 9 + kh * 3;
                acc[j] += vm * wj[0] + v0 * wj[1] + vp * wj[2];
            }
        }
    }
    float* o = out + (size_t)z * outZS;
    #pragma unroll
    for (int j = 0; j < 4; ++j)
        o[(cg * 4 + j) * 15 * 256 + h * 256 + wcol] = LEAKY(acc[j]);
}

// ---------------- CIN=64, PH=0 conv, LDS-staged ----------------
// grid (1, HOUT, NZ * (64/NCO)), block 256. Thread: 1 col, NCO couts, 1 row.
// Per chunk: 16 cins x 3 rows x 256 cols staged to LDS (48 KB) via 12
// independent float4 loads/thread; next chunk's loads issued before compute.
template<int HOUT, int NCO>
__global__ __launch_bounds__(256) void convS(
    const float* __restrict__ in, int inChS, int inZS,
    const float* __restrict__ w0, const float* __restrict__ b0,
    const float* __restrict__ w1, const float* __restrict__ b1,
    float* __restrict__ out, int outZS)
{
    constexpr int NCG = 64 / NCO;
    __shared__ float lds[16 * 3 * 256];   // 48 KB
    const int tid = threadIdx.x;
    const int h  = blockIdx.y;
    const int cg = blockIdx.z % NCG;
    const int z  = blockIdx.z / NCG;
    const float* W  = (z ? w1 : w0) + cg * NCO * 576;   // 64*9 per cout
    const float* Bv = z ? b1 : b0;
    const float* ib = in + (size_t)z * inZS + h * 256;  // + cin*inChS + kh*256
    float* o = out + (size_t)z * outZS;

    float acc[NCO];
    #pragma unroll
    for (int j = 0; j < NCO; ++j) acc[j] = Bv[cg * NCO + j];

    const bool mL = (tid > 0), mR = (tid < 255);

    float4 st[12];
    // prefetch chunk 0
    #pragma unroll
    for (int it = 0; it < 12; ++it) {
        const int f   = tid + it * 256;        // float4 unit, 0..3071
        const int row = f >> 6;                // 0..47 = cin_local*3 + kh
        const int off = (f & 63) * 4;
        st[it] = *(const float4*)(ib + (row / 3) * inChS + (row % 3) * 256 + off);
    }

    for (int c = 0; c < 4; ++c) {
        __syncthreads();                       // lds free (prev chunk's readers done)
        #pragma unroll
        for (int it = 0; it < 12; ++it) {
            const int f = tid + it * 256;
            *(float4*)&lds[f * 4] = st[it];
        }
        __syncthreads();
        if (c < 3) {                           // issue next chunk's loads early
            #pragma unroll
            for (int it = 0; it < 12; ++it) {
                const int f   = tid + it * 256;
                const int row = f >> 6;
                const int off = (f & 63) * 4;
                st[it] = *(const float4*)(ib + ((c + 1) * 16 + row / 3) * inChS
                                             + (row % 3) * 256 + off);
            }
        }
        // compute chunk c from LDS (overlaps with in-flight loads)
        #pragma unroll
        for (int cl = 0; cl < 16; ++cl) {
            #pragma unroll
            for (int kh = 0; kh < 3; ++kh) {
                const float* lr = &lds[(cl * 3 + kh) * 256];
                const float v0 = lr[tid];
                const float vm = mL ? lr[tid - 1] : 0.f;
                const float vp = mR ? lr[tid + 1] : 0.f;
                const float* wj = W + (c * 16 + cl) * 9 + kh * 3;
                #pragma unroll
                for (int j = 0; j < NCO; ++j) {
                    acc[j] += vm * wj[j * 576 + 0]
                            + v0 * wj[j * 576 + 1]
                            + vp * wj[j * 576 + 2];
                }
            }
        }
    }

    const int ohw = HOUT * 256;
    #pragma unroll
    for (int j = 0; j < NCO; ++j)
        o[(cg * NCO + j) * ohw + h * 256 + tid] = LEAKY(acc[j]);
}

// ---------------- Per-pixel 8x8 @ 8x8 ----------------
__global__ void mm88(const float* __restrict__ tw, float* __restrict__ p0)
{
    const int idx = blockIdx.x * 256 + threadIdx.x;   // pixel in 9*256
    const float* s = tw;
    const float* e = tw + 64 * 9 * 256;
    float sv[64];
    #pragma unroll
    for (int c = 0; c < 64; ++c) sv[c] = s[c * 9 * 256 + idx];
    #pragma unroll
    for (int i = 0; i < 8; ++i) {
        float ev[8];
        #pragma unroll
        for (int j = 0; j < 8; ++j) ev[j] = e[(i * 8 + j) * 9 * 256 + idx];
        #pragma unroll
        for (int k = 0; k < 8; ++k) {
            float acc = 0.f;
            #pragma unroll
            for (int j = 0; j < 8; ++j) acc += ev[j] * sv[j * 8 + k];
            p0[(i * 8 + k) * 9 * 256 + idx] = acc;
        }
    }
}

// ---------------- conv9 (64->3, kh=1 taps only) + recurrence update ----------------
// block (256,4): threadIdx.y owns 16 cins, fully unrolled; LDS reduce.
__global__ void conv9up(const float* __restrict__ pin, const float* __restrict__ w9,
                        const float* __restrict__ b9, const float* __restrict__ x,
                        float* __restrict__ ebuf, float* __restrict__ preds, int i)
{
    const int wcol = threadIdx.x;
    const int yq   = threadIdx.y;       // 0..3
    const int c0   = yq * 16;
    const bool mL = (wcol > 0), mR = (wcol < 255);
    float a0 = 0.f, a1 = 0.f, a2 = 0.f;

    #pragma unroll
    for (int c = 0; c < 16; ++c) {
        const int cin = c0 + c;
        const float* r_ = pin + cin * 256;
        float vm = mL ? r_[wcol - 1] : 0.f;
        float v0 = r_[wcol];
        float vp = mR ? r_[wcol + 1] : 0.f;
        const float* wk0 = w9 + (0 * 64 + cin) * 9 + 3;   // kh=1
        const float* wk1 = w9 + (1 * 64 + cin) * 9 + 3;
        const float* wk2 = w9 + (2 * 64 + cin) * 9 + 3;
        a0 += vm * wk0[0] + v0 * wk0[1] + vp * wk0[2];
        a1 += vm * wk1[0] + v0 * wk1[1] + vp * wk1[2];
        a2 += vm * wk2[0] + v0 * wk2[1] + vp * wk2[2];
    }

    __shared__ float red[4][3][256];
    red[yq][0][wcol] = a0;
    red[yq][1][wcol] = a1;
    red[yq][2][wcol] = a2;
    __syncthreads();

    if (yq == 0) {
        #pragma unroll
        for (int j = 0; j < 3; ++j) {
            float v = b9[j] + red[0][j][wcol] + red[1][j][wcol]
                            + red[2][j][wcol] + red[3][j][wcol];
            v = LEAKY(v);
            preds[i * 768 + j * 256 + wcol] = v;
            ebuf[j * 31 * 256 + (15 + i) * 256 + wcol] =
                x[j * 31 * 256 + (15 + i) * 256 + wcol] - v;
        }
    }
}

// ---------------- finalize ----------------
__global__ void finalize(const float* __restrict__ preds, const float* __restrict__ ebuf,
                         float* __restrict__ o)
{
    const int idx = blockIdx.x * 256 + threadIdx.x;
    if (idx >= 24576) return;
    if (idx < 12288) {
        const int c = idx >> 12;
        const int t = (idx >> 8) & 15;
        const int w = idx & 255;
        o[idx] = preds[t * 768 + c * 256 + w];
    } else {
        const int j = idx - 12288;
        const int c = j >> 12;
        const int t = (j >> 8) & 15;
        const int w = j & 255;
        o[idx] = ebuf[c * 31 * 256 + (15 + t) * 256 + w];
    }
}

extern "C" void kernel_launch(void* const* d_in, const int* in_sizes, int n_in,
                              void* d_out, int out_size, void* d_ws, size_t ws_size,
                              hipStream_t stream)
{
    const float* x   = (const float*)d_in[0];
    const float* w1x = (const float*)d_in[1];  const float* b1x = (const float*)d_in[2];
    const float* w2x = (const float*)d_in[3];  const float* b2x = (const float*)d_in[4];
    const float* w3x = (const float*)d_in[5];  const float* b3x = (const float*)d_in[6];
    const float* w4x = (const float*)d_in[7];  const float* b4x = (const float*)d_in[8];
    const float* w1e = (const float*)d_in[9];  const float* b1e = (const float*)d_in[10];
    const float* w2e = (const float*)d_in[11]; const float* b2e = (const float*)d_in[12];
    const float* w3e = (const float*)d_in[13]; const float* b3e = (const float*)d_in[14];
    const float* w4e = (const float*)d_in[15]; const float* b4e = (const float*)d_in[16];
    const float* w5  = (const float*)d_in[17]; const float* b5  = (const float*)d_in[18];
    const float* w6  = (const float*)d_in[19]; const float* b6  = (const float*)d_in[20];
    const float* w7  = (const float*)d_in[21]; const float* b7  = (const float*)d_in[22];
    const float* w8  = (const float*)d_in[23]; const float* b8  = (const float*)d_in[24];
    const float* w9  = (const float*)d_in[25]; const float* b9  = (const float*)d_in[26];

    float* ws    = (float*)d_ws;
    float* ebuf  = ws;                   // 3*31*256    = 23808
    float* tA    = ebuf + 23808;         // 2*64*15*256 = 491520
    float* tB    = tA + 491520;          // 2*64*15*256 = 491520
    float* p0    = tB + 491520;          // 64*9*256    = 147456
    float* p1    = p0 + 147456;          // 64*9*256    = 147456
    float* preds = p1 + 147456;          // 16*3*256    = 12288

    hipMemcpyAsync(ebuf, x, 23808 * sizeof(float), hipMemcpyDeviceToDevice, stream);

    for (int i = 0; i < 16; ++i) {
        conv3<<<dim3(1, 15, 32), 256, 0, stream>>>(ebuf, i, w1x, b1x, w1e, b1e,
                                                   tA, 64 * 15 * 256);
        convS<13, 4><<<dim3(1, 13, 32), 256, 0, stream>>>(tA, 15 * 256, 64 * 15 * 256,
                                                          w2x, b2x, w2e, b2e,
                                                          tB, 64 * 13 * 256);
        convS<11, 4><<<dim3(1, 11, 32), 256, 0, stream>>>(tB, 13 * 256, 64 * 13 * 256,
                                                          w3x, b3x, w3e, b3e,
                                                          tA, 64 * 11 * 256);
        convS<9, 4><<<dim3(1, 9, 32), 256, 0, stream>>>(tA, 11 * 256, 64 * 11 * 256,
                                                        w4x, b4x, w4e, b4e,
                                                        tB, 64 * 9 * 256);
        mm88<<<9, 256, 0, stream>>>(tB, p0);
        convS<7, 4><<<dim3(1, 7, 16), 256, 0, stream>>>(p0, 9 * 256, 0,
                                                        w5, b5, w5, b5, p1, 0);
        convS<5, 2><<<dim3(1, 5, 32), 256, 0, stream>>>(p1, 7 * 256, 0,
                                                        w6, b6, w6, b6, p0, 0);
        convS<3, 2><<<dim3(1, 3, 32), 256, 0, stream>>>(p0, 5 * 256, 0,
                                                        w7, b7, w7, b7, p1, 0);
        convS<1, 1><<<dim3(1, 1, 64), 256, 0, stream>>>(p1, 3 * 256, 0,
                                                        w8, b8, w8, b8, p0, 0);
        conv9up<<<dim3(1, 1, 1), dim3(256, 4), 0, stream>>>(p0, w9, b9, x, ebuf, preds, i);
    }

    finalize<<<96, 256, 0, stream>>>(preds, ebuf, (float*)d_out);
}